// Round 1
// baseline (10616.167 us; speedup 1.0000x reference)
//
#include <hip/hip_runtime.h>

typedef float f32x4 __attribute__((ext_vector_type(4)));
typedef short bf16x8 __attribute__((ext_vector_type(8)));

#define SLEN 128
#define TLEN 127
#define VOC 36
#define NPROBS (4096*127*36)
#define MLOSS_OFF NPROBS
#define LOSS_OFF (NPROBS + 4096)

// ws layout (bytes)
#define WS_W0 0                      // short[1024*384]
#define WS_W1 786432                 // short[1024*512]
#define WS_FC 1835008                // short[48*256]
#define WS_B0 1859584                // float[1024]
#define WS_B1 1863680                // float[1024]

__device__ __forceinline__ short f2bf(float f){
  unsigned u = __float_as_uint(f);
  u += 0x7fffu + ((u >> 16) & 1u);
  return (short)(u >> 16);
}
__device__ __forceinline__ float fsig(float x){ return 1.0f/(1.0f + __expf(-x)); }
__device__ __forceinline__ float ftanh(float x){ return 1.0f - 2.0f/(1.0f + __expf(2.0f*x)); }

__global__ void prep_kernel(const float* __restrict__ Wih0, const float* __restrict__ Whh0,
                            const float* __restrict__ bih0, const float* __restrict__ bhh0,
                            const float* __restrict__ Wih1, const float* __restrict__ Whh1,
                            const float* __restrict__ bih1, const float* __restrict__ bhh1,
                            const float* __restrict__ fcW,
                            short* __restrict__ w0, short* __restrict__ w1, short* __restrict__ fcw,
                            float* __restrict__ b0, float* __restrict__ b1,
                            float* __restrict__ out)
{
  int idx = blockIdx.x*256 + threadIdx.x;
  if (idx == 0) out[LOSS_OFF] = 0.0f;
  if (idx < 1024*384) {
    int r = idx/384, c = idx - r*384;
    float v = (c < 128) ? Wih0[r*128 + c] : Whh0[r*256 + (c-128)];
    w0[idx] = f2bf(v);
  } else if (idx < 1024*384 + 1024*512) {
    int i2 = idx - 1024*384;
    int r = i2/512, c = i2 - r*512;
    float v = (c < 256) ? Wih1[r*256 + c] : Whh1[r*256 + (c-256)];
    w1[i2] = f2bf(v);
  } else if (idx < 1024*384 + 1024*512 + 48*256) {
    int i2 = idx - (1024*384 + 1024*512);
    int r = i2 >> 8, c = i2 & 255;
    fcw[i2] = (r < VOC) ? f2bf(fcW[r*256 + c]) : (short)0;
  } else if (idx < 1024*384 + 1024*512 + 48*256 + 1024) {
    int i2 = idx - (1024*384 + 1024*512 + 48*256);
    b0[i2] = bih0[i2] + bhh0[i2];
  } else if (idx < 1024*384 + 1024*512 + 48*256 + 2048) {
    int i2 = idx - (1024*384 + 1024*512 + 48*256 + 1024);
    b1[i2] = bih1[i2] + bhh1[i2];
  }
}

__global__ __launch_bounds__(512, 2)
void lstm_kernel(const int* __restrict__ x, const float* __restrict__ emb,
                 const float* __restrict__ fcb,
                 const short* __restrict__ W0, const short* __restrict__ W1,
                 const short* __restrict__ FCW,
                 const float* __restrict__ b0, const float* __restrict__ b1,
                 float* __restrict__ out)
{
  __shared__ __align__(16) short emb_s[36*136];
  __shared__ __align__(16) short h0_s[64*264];
  __shared__ __align__(16) short h1_s[64*264];
  __shared__ int   tok_s[64];
  __shared__ float invlen_s[64];

  const int tid  = threadIdx.x;
  const int lane = tid & 63;
  const int wv   = tid >> 6;      // 0..7
  const int l15  = lane & 15;
  const int l4   = lane >> 4;     // 0..3
  const int r0   = blockIdx.x * 64;
  const int ch0  = wv * 32;       // wave's channel slice [ch0, ch0+32)

  // ---- prologue: emb -> LDS bf16, zero h, lengths, tok(t=0) ----
  for (int i = tid; i < 36*128; i += 512) {
    int r = i >> 7, c = i & 127;
    emb_s[r*136 + c] = f2bf(emb[i]);
  }
  for (int i = tid; i < 64*264; i += 512) { h0_s[i] = 0; h1_s[i] = 0; }
  if (tid < 64) {
    int cnt = 0;
    for (int s = 0; s < SLEN; s++) cnt += (x[(r0+tid)*SLEN + s] != 0) ? 1 : 0;
    invlen_s[tid] = 1.0f / (float)cnt;
    tok_s[tid] = x[(r0+tid)*SLEN + 0];
  }
  __syncthreads();

  float c0s[2][4][4] = {};
  float c1s[2][4][4] = {};
  float mloss[4] = {0.f,0.f,0.f,0.f};

  for (int t = 0; t < TLEN; t++) {
    int tokv[4];
    #pragma unroll
    for (int m = 0; m < 4; m++) tokv[m] = tok_s[m*16 + l15];

    // ================= Layer 0: gates = [e_t | h0] @ W0^T + b0 =================
    float hn0[2][4][4];
    #pragma unroll
    for (int s = 0; s < 2; s++) {
      f32x4 acc[4][4] = {};
      const short* w0base = W0 + (ch0 + s*16 + l15)*384 + l4*8;
      #pragma unroll
      for (int kt = 0; kt < 12; kt++) {
        bf16x8 Bf[4];
        #pragma unroll
        for (int G = 0; G < 4; G++)
          Bf[G] = *(const bf16x8*)(w0base + G*(256*384) + kt*32);
        bf16x8 Af[4];
        #pragma unroll
        for (int m = 0; m < 4; m++) {
          if (kt < 4) Af[m] = *(const bf16x8*)(emb_s + tokv[m]*136 + kt*32 + l4*8);
          else        Af[m] = *(const bf16x8*)(h0_s + (m*16 + l15)*264 + (kt-4)*32 + l4*8);
        }
        #pragma unroll
        for (int m = 0; m < 4; m++)
          #pragma unroll
          for (int G = 0; G < 4; G++)
            acc[m][G] = __builtin_amdgcn_mfma_f32_16x16x32_bf16(Af[m], Bf[G], acc[m][G], 0, 0, 0);
      }
      const int ch = ch0 + s*16 + l15;
      const float bi = b0[ch], bff = b0[256+ch], bg = b0[512+ch], bo = b0[768+ch];
      #pragma unroll
      for (int m = 0; m < 4; m++)
        #pragma unroll
        for (int j = 0; j < 4; j++) {
          float iv = fsig (acc[m][0][j] + bi);
          float fv = fsig (acc[m][1][j] + bff);
          float gv = ftanh(acc[m][2][j] + bg);
          float ov = fsig (acc[m][3][j] + bo);
          float c  = fv * c0s[s][m][j] + iv * gv;
          c0s[s][m][j] = c;
          hn0[s][m][j] = ov * ftanh(c);
        }
    }
    __syncthreads();   // all waves done reading h0(t-1) / tok(t)

    if (wv == 7) tok_s[lane] = x[(r0+lane)*SLEN + t + 1];   // stage next tokens
    #pragma unroll
    for (int s = 0; s < 2; s++) {
      const int ch = ch0 + s*16 + l15;
      #pragma unroll
      for (int m = 0; m < 4; m++)
        #pragma unroll
        for (int j = 0; j < 4; j++)
          h0_s[(m*16 + l4*4 + j)*264 + ch] = f2bf(hn0[s][m][j]);
    }
    __syncthreads();   // h0(t) visible

    // ================= Layer 1: gates = [h0 | h1] @ W1^T + b1 =================
    float hn1[2][4][4];
    #pragma unroll
    for (int s = 0; s < 2; s++) {
      f32x4 acc[4][4] = {};
      const short* w1base = W1 + (ch0 + s*16 + l15)*512 + l4*8;
      #pragma unroll
      for (int kt = 0; kt < 16; kt++) {
        bf16x8 Bf[4];
        #pragma unroll
        for (int G = 0; G < 4; G++)
          Bf[G] = *(const bf16x8*)(w1base + G*(256*512) + kt*32);
        bf16x8 Af[4];
        #pragma unroll
        for (int m = 0; m < 4; m++) {
          if (kt < 8) Af[m] = *(const bf16x8*)(h0_s + (m*16 + l15)*264 + kt*32 + l4*8);
          else        Af[m] = *(const bf16x8*)(h1_s + (m*16 + l15)*264 + (kt-8)*32 + l4*8);
        }
        #pragma unroll
        for (int m = 0; m < 4; m++)
          #pragma unroll
          for (int G = 0; G < 4; G++)
            acc[m][G] = __builtin_amdgcn_mfma_f32_16x16x32_bf16(Af[m], Bf[G], acc[m][G], 0, 0, 0);
      }
      const int ch = ch0 + s*16 + l15;
      const float bi = b1[ch], bff = b1[256+ch], bg = b1[512+ch], bo = b1[768+ch];
      #pragma unroll
      for (int m = 0; m < 4; m++)
        #pragma unroll
        for (int j = 0; j < 4; j++) {
          float iv = fsig (acc[m][0][j] + bi);
          float fv = fsig (acc[m][1][j] + bff);
          float gv = ftanh(acc[m][2][j] + bg);
          float ov = fsig (acc[m][3][j] + bo);
          float c  = fv * c1s[s][m][j] + iv * gv;
          c1s[s][m][j] = c;
          hn1[s][m][j] = ov * ftanh(c);
        }
    }
    __syncthreads();   // all waves done reading h1(t-1)

    #pragma unroll
    for (int s = 0; s < 2; s++) {
      const int ch = ch0 + s*16 + l15;
      #pragma unroll
      for (int m = 0; m < 4; m++)
        #pragma unroll
        for (int j = 0; j < 4; j++)
          h1_s[(m*16 + l4*4 + j)*264 + ch] = f2bf(hn1[s][m][j]);
    }
    __syncthreads();   // h1(t) visible

    // ================= FC + softmax + loss (waves 0-3, 16 rows each) =========
    if (wv < 4) {
      const int wr = wv * 16;
      f32x4 a3[3] = {};
      #pragma unroll
      for (int kt = 0; kt < 8; kt++) {
        bf16x8 Ah = *(const bf16x8*)(h1_s + (wr + l15)*264 + kt*32 + l4*8);
        #pragma unroll
        for (int n = 0; n < 3; n++) {
          bf16x8 Bf = *(const bf16x8*)(FCW + (n*16 + l15)*256 + kt*32 + l4*8);
          a3[n] = __builtin_amdgcn_mfma_f32_16x16x32_bf16(Ah, Bf, a3[n], 0, 0, 0);
        }
      }
      const bool v2 = (l15 < 4);
      const float lb0 = fcb[l15], lb1 = fcb[16 + l15];
      const float lb2 = v2 ? fcb[32 + l15] : 0.f;
      #pragma unroll
      for (int j = 0; j < 4; j++) {
        float g0 = fmaxf(a3[0][j] + lb0, 0.f);
        float g1 = fmaxf(a3[1][j] + lb1, 0.f);
        float g2 = v2 ? fmaxf(a3[2][j] + lb2, 0.f) : -INFINITY;
        float mx = fmaxf(fmaxf(g0, g1), g2);
        #pragma unroll
        for (int k = 1; k < 16; k <<= 1) mx = fmaxf(mx, __shfl_xor(mx, k, 64));
        float e0 = __expf(g0 - mx), e1 = __expf(g1 - mx);
        float e2 = v2 ? __expf(g2 - mx) : 0.f;
        float sm = e0 + e1 + e2;
        #pragma unroll
        for (int k = 1; k < 16; k <<= 1) sm += __shfl_xor(sm, k, 64);
        float inv = 1.0f / sm;
        int row = wr + l4*4 + j;
        float* po = out + ((size_t)(r0 + row)*TLEN + t)*VOC;
        po[l15]      = e0 * inv;
        po[16 + l15] = e1 * inv;
        if (v2) po[32 + l15] = e2 * inv;
        int tg = x[(r0 + row)*SLEN + t + 1];
        float sel = (tg < 16) ? g0 : ((tg < 32) ? g1 : g2);
        float ltg = __shfl(sel, (lane & 48) | (tg & 15), 64);
        float nll = mx + __logf(sm) - ltg;
        mloss[j] += (tg != 0) ? nll * invlen_s[row] : 0.f;
      }
    }
  } // t loop

  if (wv < 4 && l15 == 0) {
    float tot = 0.f;
    #pragma unroll
    for (int j = 0; j < 4; j++) {
      int row = wv*16 + l4*4 + j;
      out[(size_t)MLOSS_OFF + r0 + row] = mloss[j];
      tot += mloss[j];
    }
    atomicAdd(out + LOSS_OFF, tot * (1.0f/4096.0f));
  }
}

extern "C" void kernel_launch(void* const* d_in, const int* in_sizes, int n_in,
                              void* d_out, int out_size, void* d_ws, size_t ws_size,
                              hipStream_t stream) {
  const int*   x    = (const int*)  d_in[0];
  const float* emb  = (const float*)d_in[1];
  const float* Wih0 = (const float*)d_in[2];
  const float* Whh0 = (const float*)d_in[3];
  const float* bih0 = (const float*)d_in[4];
  const float* bhh0 = (const float*)d_in[5];
  const float* Wih1 = (const float*)d_in[6];
  const float* Whh1 = (const float*)d_in[7];
  const float* bih1 = (const float*)d_in[8];
  const float* bhh1 = (const float*)d_in[9];
  const float* fcW  = (const float*)d_in[10];
  const float* fcb  = (const float*)d_in[11];

  short* w0  = (short*)((char*)d_ws + WS_W0);
  short* w1  = (short*)((char*)d_ws + WS_W1);
  short* fcw = (short*)((char*)d_ws + WS_FC);
  float* b0  = (float*)((char*)d_ws + WS_B0);
  float* b1  = (float*)((char*)d_ws + WS_B1);
  float* out = (float*)d_out;

  prep_kernel<<<3640, 256, 0, stream>>>(Wih0, Whh0, bih0, bhh0, Wih1, Whh1,
                                        bih1, bhh1, fcW, w0, w1, fcw, b0, b1, out);
  lstm_kernel<<<64, 512, 0, stream>>>(x, emb, fcb, w0, w1, fcw, b0, b1, out);
}

// Round 2
// 10346.229 us; speedup vs baseline: 1.0261x; 1.0261x over previous
//
#include <hip/hip_runtime.h>

typedef float f32x4 __attribute__((ext_vector_type(4)));
typedef short bf16x8 __attribute__((ext_vector_type(8)));

#define SLEN 128
#define TLEN 127
#define VOC 36
#define NPROBS (4096*127*36)
#define MLOSS_OFF NPROBS
#define LOSS_OFF (NPROBS + 4096)

#define ROWS 32          // rows per block
#define NBLK 128

// ws layout (bytes)
#define WS_W0 0                      // short[1024*384]
#define WS_W1 786432                 // short[1024*512]
#define WS_FC 1835008                // short[48*256]
#define WS_B0 1859584                // float[1024]
#define WS_B1 1863680                // float[1024]

__device__ __forceinline__ short f2bf(float f){
  unsigned u = __float_as_uint(f);
  u += 0x7fffu + ((u >> 16) & 1u);
  return (short)(u >> 16);
}
__device__ __forceinline__ float fsig(float x){ return 1.0f/(1.0f + __expf(-x)); }
__device__ __forceinline__ float ftanh(float x){ return 1.0f - 2.0f/(1.0f + __expf(2.0f*x)); }

__global__ void prep_kernel(const float* __restrict__ Wih0, const float* __restrict__ Whh0,
                            const float* __restrict__ bih0, const float* __restrict__ bhh0,
                            const float* __restrict__ Wih1, const float* __restrict__ Whh1,
                            const float* __restrict__ bih1, const float* __restrict__ bhh1,
                            const float* __restrict__ fcW,
                            short* __restrict__ w0, short* __restrict__ w1, short* __restrict__ fcw,
                            float* __restrict__ b0, float* __restrict__ b1,
                            float* __restrict__ out)
{
  int idx = blockIdx.x*256 + threadIdx.x;
  if (idx == 0) out[LOSS_OFF] = 0.0f;
  if (idx < 1024*384) {
    int r = idx/384, c = idx - r*384;
    float v = (c < 128) ? Wih0[r*128 + c] : Whh0[r*256 + (c-128)];
    w0[idx] = f2bf(v);
  } else if (idx < 1024*384 + 1024*512) {
    int i2 = idx - 1024*384;
    int r = i2/512, c = i2 - r*512;
    float v = (c < 256) ? Wih1[r*256 + c] : Whh1[r*256 + (c-256)];
    w1[i2] = f2bf(v);
  } else if (idx < 1024*384 + 1024*512 + 48*256) {
    int i2 = idx - (1024*384 + 1024*512);
    int r = i2 >> 8, c = i2 & 255;
    fcw[i2] = (r < VOC) ? f2bf(fcW[r*256 + c]) : (short)0;
  } else if (idx < 1024*384 + 1024*512 + 48*256 + 1024) {
    int i2 = idx - (1024*384 + 1024*512 + 48*256);
    b0[i2] = bih0[i2] + bhh0[i2];
  } else if (idx < 1024*384 + 1024*512 + 48*256 + 2048) {
    int i2 = idx - (1024*384 + 1024*512 + 48*256 + 1024);
    b1[i2] = bih1[i2] + bhh1[i2];
  }
}

// 16 waves (4/SIMD): wave wv owns 16 gate-channels ch0=wv*16 for BOTH layers.
// 32 batch rows per block -> m-loop = 2 MFMA row-tiles.
__global__ __launch_bounds__(1024, 4)
void lstm_kernel(const int* __restrict__ x, const float* __restrict__ emb,
                 const float* __restrict__ fcb,
                 const short* __restrict__ W0, const short* __restrict__ W1,
                 const short* __restrict__ FCW,
                 const float* __restrict__ b0, const float* __restrict__ b1,
                 float* __restrict__ out)
{
  __shared__ __align__(16) short emb_s[36*136];
  __shared__ __align__(16) short h0_s[ROWS*264];
  __shared__ __align__(16) short h1_s[ROWS*264];
  __shared__ int   tok_s[ROWS];
  __shared__ float invlen_s[ROWS];

  const int tid  = threadIdx.x;
  const int lane = tid & 63;
  const int wv   = tid >> 6;      // 0..15
  const int l15  = lane & 15;
  const int l4   = lane >> 4;     // 0..3
  const int r0   = blockIdx.x * ROWS;
  const int ch0  = wv * 16;       // wave's channel slice [ch0, ch0+16)

  // ---- prologue ----
  for (int i = tid; i < 36*128; i += 1024) {
    int r = i >> 7, c = i & 127;
    emb_s[r*136 + c] = f2bf(emb[i]);
  }
  for (int i = tid; i < ROWS*264; i += 1024) { h0_s[i] = 0; h1_s[i] = 0; }
  if (tid < ROWS) {
    int cnt = 0;
    for (int s = 0; s < SLEN; s++) cnt += (x[(r0+tid)*SLEN + s] != 0) ? 1 : 0;
    invlen_s[tid] = 1.0f / (float)cnt;
    tok_s[tid] = x[(r0+tid)*SLEN + 0];
  }
  __syncthreads();

  // invariant hoists
  const int ch = ch0 + l15;
  const short* w0base = W0 + ch*384 + l4*8;
  const short* w1base = W1 + ch*512 + l4*8;
  const float bi0 = b0[ch],     bf0 = b0[256+ch], bg0 = b0[512+ch], bo0 = b0[768+ch];
  const float bi1 = b1[ch],     bf1 = b1[256+ch], bg1 = b1[512+ch], bo1 = b1[768+ch];
  const bool  v2  = (l15 < 4);
  const float lb0 = fcb[l15], lb1 = fcb[16 + l15];
  const float lb2 = v2 ? fcb[32 + l15] : 0.f;

  float c0s[2][4] = {};
  float c1s[2][4] = {};
  float mloss[4] = {0.f,0.f,0.f,0.f};

  for (int t = 0; t < TLEN; t++) {
    int tokv[2];
    #pragma unroll
    for (int m = 0; m < 2; m++) tokv[m] = tok_s[m*16 + l15];

    // ================= Layer 0: gates = [e_t | h0] @ W0^T + b0 =================
    float hn0[2][4];
    {
      f32x4 acc[2][4] = {};
      #pragma unroll
      for (int kt = 0; kt < 12; kt++) {
        bf16x8 Bf[4];
        #pragma unroll
        for (int G = 0; G < 4; G++)
          Bf[G] = *(const bf16x8*)(w0base + G*(256*384) + kt*32);
        bf16x8 Af[2];
        #pragma unroll
        for (int m = 0; m < 2; m++) {
          if (kt < 4) Af[m] = *(const bf16x8*)(emb_s + tokv[m]*136 + kt*32 + l4*8);
          else        Af[m] = *(const bf16x8*)(h0_s + (m*16 + l15)*264 + (kt-4)*32 + l4*8);
        }
        #pragma unroll
        for (int m = 0; m < 2; m++)
          #pragma unroll
          for (int G = 0; G < 4; G++)
            acc[m][G] = __builtin_amdgcn_mfma_f32_16x16x32_bf16(Af[m], Bf[G], acc[m][G], 0, 0, 0);
      }
      #pragma unroll
      for (int m = 0; m < 2; m++)
        #pragma unroll
        for (int j = 0; j < 4; j++) {
          float iv = fsig (acc[m][0][j] + bi0);
          float fv = fsig (acc[m][1][j] + bf0);
          float gv = ftanh(acc[m][2][j] + bg0);
          float ov = fsig (acc[m][3][j] + bo0);
          float c  = fv * c0s[m][j] + iv * gv;
          c0s[m][j] = c;
          hn0[m][j] = ov * ftanh(c);
        }
    }
    __syncthreads();   // b1: all waves done reading h0(t-1), tok(t)

    if (wv == 15 && lane < ROWS) tok_s[lane] = x[(r0+lane)*SLEN + t + 1];
    #pragma unroll
    for (int m = 0; m < 2; m++)
      #pragma unroll
      for (int j = 0; j < 4; j++)
        h0_s[(m*16 + l4*4 + j)*264 + ch] = f2bf(hn0[m][j]);
    __syncthreads();   // b2: h0(t) + tok(t+1) visible

    // ================= Layer 1: gates = [h0 | h1] @ W1^T + b1 =================
    float hn1[2][4];
    {
      f32x4 acc[2][4] = {};
      #pragma unroll
      for (int kt = 0; kt < 16; kt++) {
        bf16x8 Bf[4];
        #pragma unroll
        for (int G = 0; G < 4; G++)
          Bf[G] = *(const bf16x8*)(w1base + G*(256*512) + kt*32);
        bf16x8 Af[2];
        #pragma unroll
        for (int m = 0; m < 2; m++) {
          if (kt < 8) Af[m] = *(const bf16x8*)(h0_s + (m*16 + l15)*264 + kt*32 + l4*8);
          else        Af[m] = *(const bf16x8*)(h1_s + (m*16 + l15)*264 + (kt-8)*32 + l4*8);
        }
        #pragma unroll
        for (int m = 0; m < 2; m++)
          #pragma unroll
          for (int G = 0; G < 4; G++)
            acc[m][G] = __builtin_amdgcn_mfma_f32_16x16x32_bf16(Af[m], Bf[G], acc[m][G], 0, 0, 0);
      }
      #pragma unroll
      for (int m = 0; m < 2; m++)
        #pragma unroll
        for (int j = 0; j < 4; j++) {
          float iv = fsig (acc[m][0][j] + bi1);
          float fv = fsig (acc[m][1][j] + bf1);
          float gv = ftanh(acc[m][2][j] + bg1);
          float ov = fsig (acc[m][3][j] + bo1);
          float c  = fv * c1s[m][j] + iv * gv;
          c1s[m][j] = c;
          hn1[m][j] = ov * ftanh(c);
        }
    }
    __syncthreads();   // b3: all waves done reading h1(t-1)

    #pragma unroll
    for (int m = 0; m < 2; m++)
      #pragma unroll
      for (int j = 0; j < 4; j++)
        h1_s[(m*16 + l4*4 + j)*264 + ch] = f2bf(hn1[m][j]);
    __syncthreads();   // b4: h1(t) visible

    // ===== FC + softmax + loss: waves 0-1 only; others run ahead into L0(t+1)
    if (wv < 2) {
      const int wr = wv * 16;
      f32x4 a3[3] = {};
      #pragma unroll
      for (int kt = 0; kt < 8; kt++) {
        bf16x8 Ah = *(const bf16x8*)(h1_s + (wr + l15)*264 + kt*32 + l4*8);
        #pragma unroll
        for (int n = 0; n < 3; n++) {
          bf16x8 Bf = *(const bf16x8*)(FCW + (n*16 + l15)*256 + kt*32 + l4*8);
          a3[n] = __builtin_amdgcn_mfma_f32_16x16x32_bf16(Ah, Bf, a3[n], 0, 0, 0);
        }
      }
      #pragma unroll
      for (int j = 0; j < 4; j++) {
        float g0 = fmaxf(a3[0][j] + lb0, 0.f);
        float g1 = fmaxf(a3[1][j] + lb1, 0.f);
        float g2 = v2 ? fmaxf(a3[2][j] + lb2, 0.f) : -INFINITY;
        float mx = fmaxf(fmaxf(g0, g1), g2);
        #pragma unroll
        for (int k = 1; k < 16; k <<= 1) mx = fmaxf(mx, __shfl_xor(mx, k, 64));
        float e0 = __expf(g0 - mx), e1 = __expf(g1 - mx);
        float e2 = v2 ? __expf(g2 - mx) : 0.f;
        float sm = e0 + e1 + e2;
        #pragma unroll
        for (int k = 1; k < 16; k <<= 1) sm += __shfl_xor(sm, k, 64);
        float inv = 1.0f / sm;
        int row = wr + l4*4 + j;
        float* po = out + ((size_t)(r0 + row)*TLEN + t)*VOC;
        __builtin_nontemporal_store(e0 * inv, po + l15);
        __builtin_nontemporal_store(e1 * inv, po + 16 + l15);
        if (v2) __builtin_nontemporal_store(e2 * inv, po + 32 + l15);
        int tg = tok_s[row];                       // holds x[.., t+1] now
        float sel = (tg < 16) ? g0 : ((tg < 32) ? g1 : g2);
        float ltg = __shfl(sel, (lane & 48) | (tg & 15), 64);
        float nll = mx + __logf(sm) - ltg;
        mloss[j] += (tg != 0) ? nll * invlen_s[row] : 0.f;
      }
    }
  } // t loop

  if (wv < 2 && l15 == 0) {
    float tot = 0.f;
    #pragma unroll
    for (int j = 0; j < 4; j++) {
      int row = wv*16 + l4*4 + j;
      __builtin_nontemporal_store(mloss[j], out + (size_t)MLOSS_OFF + r0 + row);
      tot += mloss[j];
    }
    atomicAdd(out + LOSS_OFF, tot * (1.0f/4096.0f));
  }
}

extern "C" void kernel_launch(void* const* d_in, const int* in_sizes, int n_in,
                              void* d_out, int out_size, void* d_ws, size_t ws_size,
                              hipStream_t stream) {
  const int*   x    = (const int*)  d_in[0];
  const float* emb  = (const float*)d_in[1];
  const float* Wih0 = (const float*)d_in[2];
  const float* Whh0 = (const float*)d_in[3];
  const float* bih0 = (const float*)d_in[4];
  const float* bhh0 = (const float*)d_in[5];
  const float* Wih1 = (const float*)d_in[6];
  const float* Whh1 = (const float*)d_in[7];
  const float* bih1 = (const float*)d_in[8];
  const float* bhh1 = (const float*)d_in[9];
  const float* fcW  = (const float*)d_in[10];
  const float* fcb  = (const float*)d_in[11];

  short* w0  = (short*)((char*)d_ws + WS_W0);
  short* w1  = (short*)((char*)d_ws + WS_W1);
  short* fcw = (short*)((char*)d_ws + WS_FC);
  float* b0  = (float*)((char*)d_ws + WS_B0);
  float* b1  = (float*)((char*)d_ws + WS_B1);
  float* out = (float*)d_out;

  prep_kernel<<<3640, 256, 0, stream>>>(Wih0, Whh0, bih0, bhh0, Wih1, Whh1,
                                        bih1, bhh1, fcW, w0, w1, fcw, b0, b1, out);
  lstm_kernel<<<NBLK, 1024, 0, stream>>>(x, emb, fcb, w0, w1, fcw, b0, b1, out);
}